// Round 9
// baseline (148.169 us; speedup 1.0000x reference)
//
#include <hip/hip_runtime.h>
#include <hip/hip_fp16.h>

// GradientsLeastSquares — R9 = R8 + 8 edges/thread (2 lanes/node) + SoA M.
// Evidence: kernels run ~2 TB/s effective vs 185 MB ideal traffic -> latency/
// request-bound. 8 independent gathers per thread (was 4) raises in-flight
// requests ~1.7x net of the VGPR/occupancy cost; reduction is 1 shfl_xor.
// M split into f32x4 + f32x2 planes: 24 B/node, alignment preserved.
//
// ws: P1 float4[N] 4.8 | Gh u32x2[N] 2.4 | M0 f32x4[N] 4.8 | M1 f32x2[N] 2.4
//     | WXY u32[E] 19.2 | WZ u32[E/2] 9.6   = 43.2 MB

constexpr int N_NODES = 300000;
constexpr int DEG = 16;
constexpr float EPS_W = 1e-12f;
constexpr double EPS_A = 1e-8;

typedef float        f32x4 __attribute__((ext_vector_type(4)));
typedef float        f32x2 __attribute__((ext_vector_type(2)));
typedef int          i32x4 __attribute__((ext_vector_type(4)));
typedef unsigned int u32x4 __attribute__((ext_vector_type(4)));
typedef unsigned int u32x2 __attribute__((ext_vector_type(2)));

__device__ __forceinline__ float redux2(float v) {
    return v + __shfl_xor(v, 1, 2);
}

__device__ __forceinline__ unsigned int pack_h2(float a, float b) {
    union { __half2 h2; unsigned int ui; } pk;
    pk.h2 = __halves2half2(__float2half_rn(a), __float2half_rn(b));
    return pk.ui;
}

__device__ __forceinline__ f32x2 unpack_h2(unsigned int v) {
    union { __half2 h2; unsigned int ui; } pk;
    pk.ui = v;
    f32x2 r = { __low2float(pk.h2), __high2float(pk.h2) };
    return r;
}

// ---------------- Pack: P1[i] = {cx,cy,cz,u} ----------------
__global__ __launch_bounds__(256) void pack_p1(
    const float* __restrict__ coords,
    const float* __restrict__ u,
    float4* __restrict__ p1)
{
    int i = blockIdx.x * 256 + threadIdx.x;
    if (i >= N_NODES) return;
    p1[i] = make_float4(coords[3 * i], coords[3 * i + 1],
                        coords[3 * i + 2], u[i]);
}

// ---------------- Pass 1: 8 edges/thread; exports Gh/M0/M1/WXY/WZ ----------
__global__ __launch_bounds__(256) void lsq_pass1(
    const float4*  __restrict__ P,
    const int*     __restrict__ indices,
    u32x2*         __restrict__ Gh,    // f16 {g0,g1,g2,0} per node
    f32x4*         __restrict__ M0,    // {m00,m01,m02,m11}
    f32x2*         __restrict__ M1,    // {m12,m22}
    unsigned int*  __restrict__ WXY,   // half2{wx,wy} per edge
    unsigned int*  __restrict__ WZ)    // 2x f16 wz per u32
{
    int tid  = blockIdx.x * 256 + threadIdx.x;
    int node = tid >> 1;
    int h    = tid & 1;
    if (node >= N_NODES) return;

    float4 c = P[node];
    int ebase = node * DEG + h * 8;
    i32x4 ia = __builtin_nontemporal_load((const i32x4*)(indices + ebase));
    i32x4 ib = __builtin_nontemporal_load((const i32x4*)(indices + ebase + 4));

    // 8 independent gathers in flight
    float4 nb[8];
    nb[0] = P[ia.x]; nb[1] = P[ia.y]; nb[2] = P[ia.z]; nb[3] = P[ia.w];
    nb[4] = P[ib.x]; nb[5] = P[ib.y]; nb[6] = P[ib.z]; nb[7] = P[ib.w];

    float a00 = 0, a01 = 0, a02 = 0, a11 = 0, a12 = 0, a22 = 0;
    float b0 = 0, b1 = 0, b2 = 0;
    float wxs[8], wys[8], wzs[8];
    #pragma unroll
    for (int k = 0; k < 8; ++k) {
        float dx = nb[k].x - c.x, dy = nb[k].y - c.y;
        float dz = nb[k].z - c.z, dv = nb[k].w - c.w;
        float w = 1.0f / fmaxf(dx * dx + dy * dy + dz * dz, EPS_W);
        float wx = w * dx, wy = w * dy, wz = w * dz;
        wxs[k] = wx; wys[k] = wy; wzs[k] = wz;
        a00 += wx * dx; a01 += wx * dy; a02 += wx * dz;
        a11 += wy * dy; a12 += wy * dz; a22 += wz * dz;
        b0 += wx * dv; b1 += wy * dv; b2 += wz * dv;
    }

    u32x4 wxyA = { pack_h2(wxs[0], wys[0]), pack_h2(wxs[1], wys[1]),
                   pack_h2(wxs[2], wys[2]), pack_h2(wxs[3], wys[3]) };
    u32x4 wxyB = { pack_h2(wxs[4], wys[4]), pack_h2(wxs[5], wys[5]),
                   pack_h2(wxs[6], wys[6]), pack_h2(wxs[7], wys[7]) };
    __builtin_nontemporal_store(wxyA, (u32x4*)(WXY + ebase));
    __builtin_nontemporal_store(wxyB, (u32x4*)(WXY + ebase + 4));
    u32x4 wzp = { pack_h2(wzs[0], wzs[1]), pack_h2(wzs[2], wzs[3]),
                  pack_h2(wzs[4], wzs[5]), pack_h2(wzs[6], wzs[7]) };
    __builtin_nontemporal_store(wzp, (u32x4*)(WZ + (ebase >> 1)));

    a00 = redux2(a00); a01 = redux2(a01); a02 = redux2(a02);
    a11 = redux2(a11); a12 = redux2(a12); a22 = redux2(a22);
    b0 = redux2(b0); b1 = redux2(b1); b2 = redux2(b2);

    if (h == 0) {
        double A00 = (double)a00 + EPS_A;
        double A11 = (double)a11 + EPS_A;
        double A22 = (double)a22 + EPS_A;
        double A01 = (double)a01, A02 = (double)a02, A12 = (double)a12;
        double j00 = A11 * A22 - A12 * A12;
        double j01 = A02 * A12 - A01 * A22;
        double j02 = A01 * A12 - A02 * A11;
        double j11 = A00 * A22 - A02 * A02;
        double j12 = A01 * A02 - A00 * A12;
        double j22 = A00 * A11 - A01 * A01;
        double det = A00 * j00 + A01 * j01 + A02 * j02;
        double inv = 1.0 / det;
        float m00 = (float)(j00 * inv), m01 = (float)(j01 * inv);
        float m02 = (float)(j02 * inv), m11 = (float)(j11 * inv);
        float m12 = (float)(j12 * inv), m22 = (float)(j22 * inv);
        float g0 = m00 * b0 + m01 * b1 + m02 * b2;
        float g1 = m01 * b0 + m11 * b1 + m12 * b2;
        float g2 = m02 * b0 + m12 * b1 + m22 * b2;
        u32x2 gp = { pack_h2(g0, g1), pack_h2(g2, 0.0f) };
        Gh[node] = gp;                        // cached (pass2 gather target)
        f32x4 mv0 = {m00, m01, m02, m11};
        f32x2 mv1 = {m12, m22};
        __builtin_nontemporal_store(mv0, M0 + node);
        __builtin_nontemporal_store(mv1, M1 + node);
    }
}

// ---------------- Pass 2: 8 edges/thread; gather set 2.4 MB ----------------
__global__ __launch_bounds__(256) void lsq_pass2(
    const u32x2*        __restrict__ Gh,
    const f32x4*        __restrict__ M0,
    const f32x2*        __restrict__ M1,
    const unsigned int* __restrict__ WXY,
    const unsigned int* __restrict__ WZ,
    const int*          __restrict__ indices,
    float*              __restrict__ out)   // [N,6]: xx,yy,zz,xy,xz,yz
{
    int tid  = blockIdx.x * 256 + threadIdx.x;
    int node = tid >> 1;
    int h    = tid & 1;
    if (node >= N_NODES) return;

    u32x2 gip = Gh[node];
    f32x2 gi01 = unpack_h2(gip.x);
    f32x2 gi2_ = unpack_h2(gip.y);
    float gi0 = gi01.x, gi1 = gi01.y, gi2 = gi2_.x;

    int ebase = node * DEG + h * 8;
    i32x4 ia = __builtin_nontemporal_load((const i32x4*)(indices + ebase));
    i32x4 ib = __builtin_nontemporal_load((const i32x4*)(indices + ebase + 4));
    u32x4 wxyA = __builtin_nontemporal_load((const u32x4*)(WXY + ebase));
    u32x4 wxyB = __builtin_nontemporal_load((const u32x4*)(WXY + ebase + 4));
    u32x4 wzp  = __builtin_nontemporal_load((const u32x4*)(WZ + (ebase >> 1)));

    // 8 independent gathers in flight (all ~L2-hit: 2.4 MB set)
    u32x2 gb[8];
    gb[0] = Gh[ia.x]; gb[1] = Gh[ia.y]; gb[2] = Gh[ia.z]; gb[3] = Gh[ia.w];
    gb[4] = Gh[ib.x]; gb[5] = Gh[ib.y]; gb[6] = Gh[ib.z]; gb[7] = Gh[ib.w];

    float b00 = 0, b10 = 0, b20 = 0;
    float b01 = 0, b11 = 0, b21 = 0;
    float b02 = 0, b12 = 0, b22 = 0;
    unsigned int wxys[8] = {wxyA.x, wxyA.y, wxyA.z, wxyA.w,
                            wxyB.x, wxyB.y, wxyB.z, wxyB.w};
    unsigned int wzs[4] = {wzp.x, wzp.y, wzp.z, wzp.w};
    #pragma unroll
    for (int k = 0; k < 8; ++k) {
        f32x2 wxyf = unpack_h2(wxys[k]);
        f32x2 wzf  = unpack_h2(wzs[k >> 1]);
        float wx = wxyf.x, wy = wxyf.y;
        float wz = (k & 1) ? wzf.y : wzf.x;
        f32x2 gj01 = unpack_h2(gb[k].x);
        f32x2 gj2_ = unpack_h2(gb[k].y);
        float dv0 = gj01.x - gi0, dv1 = gj01.y - gi1, dv2 = gj2_.x - gi2;
        b00 += wx * dv0; b10 += wy * dv0; b20 += wz * dv0;
        b01 += wx * dv1; b11 += wy * dv1; b21 += wz * dv1;
        b02 += wx * dv2; b12 += wy * dv2; b22 += wz * dv2;
    }

    b00 = redux2(b00); b10 = redux2(b10); b20 = redux2(b20);
    b01 = redux2(b01); b11 = redux2(b11); b21 = redux2(b21);
    b02 = redux2(b02); b12 = redux2(b12); b22 = redux2(b22);

    if (h == 0) {
        f32x4 m0 = __builtin_nontemporal_load(M0 + node);
        f32x2 m1 = __builtin_nontemporal_load(M1 + node);
        float m00 = m0.x, m01 = m0.y, m02 = m0.z, m11 = m0.w;
        float m12 = m1.x, m22 = m1.y;
        float x00 = m00 * b00 + m01 * b10 + m02 * b20; // xx
        float x10 = m01 * b00 + m11 * b10 + m12 * b20; // xy
        float x20 = m02 * b00 + m12 * b10 + m22 * b20; // xz
        float x11 = m01 * b01 + m11 * b11 + m12 * b21; // yy
        float x21 = m02 * b01 + m12 * b11 + m22 * b21; // yz
        float x22 = m02 * b02 + m12 * b12 + m22 * b22; // zz
        f32x2* o2 = (f32x2*)(out + 6 * node);
        f32x2 o0 = {x00, x11};
        f32x2 o1 = {x22, x10};
        f32x2 o2v = {x20, x21};
        __builtin_nontemporal_store(o0,  o2 + 0);
        __builtin_nontemporal_store(o1,  o2 + 1);
        __builtin_nontemporal_store(o2v, o2 + 2);
    }
}

extern "C" void kernel_launch(void* const* d_in, const int* in_sizes, int n_in,
                              void* d_out, int out_size, void* d_ws, size_t ws_size,
                              hipStream_t stream) {
    const float* coords  = (const float*)d_in[0];
    const float* u       = (const float*)d_in[1];
    const int*   indices = (const int*)d_in[3];
    float*       out     = (float*)d_out;

    char* ws = (char*)d_ws;
    const size_t szP1  = (size_t)N_NODES * 16;           // 4.8 MB
    const size_t szGh  = (size_t)N_NODES * 8;            // 2.4 MB
    const size_t szM0  = (size_t)N_NODES * 16;           // 4.8 MB
    const size_t szM1  = (size_t)N_NODES * 8;            // 2.4 MB
    const size_t szWXY = (size_t)N_NODES * DEG * 4;      // 19.2 MB

    float4*       P1  = (float4*)ws;
    u32x2*        Gh  = (u32x2*)(ws + szP1);
    f32x4*        M0  = (f32x4*)(ws + szP1 + szGh);
    f32x2*        M1  = (f32x2*)(ws + szP1 + szGh + szM0);
    unsigned int* WXY = (unsigned int*)(ws + szP1 + szGh + szM0 + szM1);
    unsigned int* WZ  = (unsigned int*)(ws + szP1 + szGh + szM0 + szM1 + szWXY);

    const int block = 256;
    const int grid_nodes = (N_NODES + block - 1) / block;
    const int threads2 = N_NODES * 2;                    // 600,000
    const int grid2 = (threads2 + block - 1) / block;    // 2344

    pack_p1<<<grid_nodes, block, 0, stream>>>(coords, u, P1);
    lsq_pass1<<<grid2, block, 0, stream>>>(P1, indices, Gh, M0, M1, WXY, WZ);
    lsq_pass2<<<grid2, block, 0, stream>>>(Gh, M0, M1, WXY, WZ, indices, out);
}

// Round 10
// 144.133 us; speedup vs baseline: 1.0280x; 1.0280x over previous
//
#include <hip/hip_runtime.h>
#include <hip/hip_fp16.h>

// GradientsLeastSquares — R10 = revert to R8 (measured optimum).
// Ladder: R1 206us -> R2 166 (packed float4 gathers, NT idx) -> R4 160.8
// (wdx/M export, pass2 gathers only G) -> R7 151.2 (4 edges/thread, SoA wdx)
// -> R8 144.7 (f16 G: 2.4MB gather set < 4.19MB per-XCD L2) -> R9 148.2
// (8 edges/thread REGRESSED: request pipe already saturated at 4/thread).
// Fixed harness cost ~55us (268MB ws re-poison fill); kernels ~90us at the
// gather-request ceiling (MLP, set-size, bytes levers all individually maxed).
//
// ws: P1 float4[N] 4.8 | Gh u32x2[N] 2.4 | M0 f32x4[N] 4.8 | M1 f32x2[N] 2.4
//     | WXY u32[E] 19.2 | WZ u32[E/2] 9.6   = 43.2 MB

constexpr int N_NODES = 300000;
constexpr int DEG = 16;
constexpr float EPS_W = 1e-12f;
constexpr double EPS_A = 1e-8;

typedef float        f32x4 __attribute__((ext_vector_type(4)));
typedef float        f32x2 __attribute__((ext_vector_type(2)));
typedef int          i32x4 __attribute__((ext_vector_type(4)));
typedef unsigned int u32x4 __attribute__((ext_vector_type(4)));
typedef unsigned int u32x2 __attribute__((ext_vector_type(2)));

__device__ __forceinline__ float redux4(float v) {
    v += __shfl_xor(v, 1, 4);
    v += __shfl_xor(v, 2, 4);
    return v;
}

__device__ __forceinline__ unsigned int pack_h2(float a, float b) {
    union { __half2 h2; unsigned int ui; } pk;
    pk.h2 = __halves2half2(__float2half_rn(a), __float2half_rn(b));
    return pk.ui;
}

__device__ __forceinline__ f32x2 unpack_h2(unsigned int v) {
    union { __half2 h2; unsigned int ui; } pk;
    pk.ui = v;
    f32x2 r = { __low2float(pk.h2), __high2float(pk.h2) };
    return r;
}

// ---------------- Pack: P1[i] = {cx,cy,cz,u} ----------------
__global__ __launch_bounds__(256) void pack_p1(
    const float* __restrict__ coords,
    const float* __restrict__ u,
    float4* __restrict__ p1)
{
    int i = blockIdx.x * 256 + threadIdx.x;
    if (i >= N_NODES) return;
    p1[i] = make_float4(coords[3 * i], coords[3 * i + 1],
                        coords[3 * i + 2], u[i]);
}

// ---------------- Pass 1: 4 edges/thread; exports Gh/M0/M1/WXY/WZ ----------
__global__ __launch_bounds__(256) void lsq_pass1(
    const float4*  __restrict__ P,
    const int*     __restrict__ indices,
    u32x2*         __restrict__ Gh,    // f16 {g0,g1,g2,0} per node
    f32x4*         __restrict__ M0,    // {m00,m01,m02,m11}
    f32x2*         __restrict__ M1,    // {m12,m22}
    unsigned int*  __restrict__ WXY,   // half2{wx,wy} per edge
    unsigned int*  __restrict__ WZ)    // 2x f16 wz per u32
{
    int tid  = blockIdx.x * 256 + threadIdx.x;
    int node = tid >> 2;
    int q    = tid & 3;
    if (node >= N_NODES) return;

    float4 c = P[node];
    int ebase = node * DEG + q * 4;
    i32x4 idx = __builtin_nontemporal_load((const i32x4*)(indices + ebase));

    // 4 independent gathers in flight (the measured MLP sweet spot)
    float4 nb[4];
    nb[0] = P[idx.x]; nb[1] = P[idx.y]; nb[2] = P[idx.z]; nb[3] = P[idx.w];

    float a00 = 0, a01 = 0, a02 = 0, a11 = 0, a12 = 0, a22 = 0;
    float b0 = 0, b1 = 0, b2 = 0;
    float wxs[4], wys[4], wzs[4];
    #pragma unroll
    for (int k = 0; k < 4; ++k) {
        float dx = nb[k].x - c.x, dy = nb[k].y - c.y;
        float dz = nb[k].z - c.z, dv = nb[k].w - c.w;
        float w = 1.0f / fmaxf(dx * dx + dy * dy + dz * dz, EPS_W);
        float wx = w * dx, wy = w * dy, wz = w * dz;
        wxs[k] = wx; wys[k] = wy; wzs[k] = wz;
        a00 += wx * dx; a01 += wx * dy; a02 += wx * dz;
        a11 += wy * dy; a12 += wy * dz; a22 += wz * dz;
        b0 += wx * dv; b1 += wy * dv; b2 += wz * dv;
    }

    u32x4 wxy = { pack_h2(wxs[0], wys[0]), pack_h2(wxs[1], wys[1]),
                  pack_h2(wxs[2], wys[2]), pack_h2(wxs[3], wys[3]) };
    __builtin_nontemporal_store(wxy, (u32x4*)(WXY + ebase));
    u32x2 wzp = { pack_h2(wzs[0], wzs[1]), pack_h2(wzs[2], wzs[3]) };
    __builtin_nontemporal_store(wzp, (u32x2*)(WZ + (ebase >> 1)));

    a00 = redux4(a00); a01 = redux4(a01); a02 = redux4(a02);
    a11 = redux4(a11); a12 = redux4(a12); a22 = redux4(a22);
    b0 = redux4(b0); b1 = redux4(b1); b2 = redux4(b2);

    if (q == 0) {
        double A00 = (double)a00 + EPS_A;
        double A11 = (double)a11 + EPS_A;
        double A22 = (double)a22 + EPS_A;
        double A01 = (double)a01, A02 = (double)a02, A12 = (double)a12;
        double j00 = A11 * A22 - A12 * A12;
        double j01 = A02 * A12 - A01 * A22;
        double j02 = A01 * A12 - A02 * A11;
        double j11 = A00 * A22 - A02 * A02;
        double j12 = A01 * A02 - A00 * A12;
        double j22 = A00 * A11 - A01 * A01;
        double det = A00 * j00 + A01 * j01 + A02 * j02;
        double inv = 1.0 / det;
        float m00 = (float)(j00 * inv), m01 = (float)(j01 * inv);
        float m02 = (float)(j02 * inv), m11 = (float)(j11 * inv);
        float m12 = (float)(j12 * inv), m22 = (float)(j22 * inv);
        float g0 = m00 * b0 + m01 * b1 + m02 * b2;
        float g1 = m01 * b0 + m11 * b1 + m12 * b2;
        float g2 = m02 * b0 + m12 * b1 + m22 * b2;
        u32x2 gp = { pack_h2(g0, g1), pack_h2(g2, 0.0f) };
        Gh[node] = gp;                        // cached (pass2 gather target)
        f32x4 mv0 = {m00, m01, m02, m11};
        f32x2 mv1 = {m12, m22};
        __builtin_nontemporal_store(mv0, M0 + node);
        __builtin_nontemporal_store(mv1, M1 + node);
    }
}

// ---------------- Pass 2: 4 edges/thread; gather set 2.4 MB (L2-resident) ----
__global__ __launch_bounds__(256) void lsq_pass2(
    const u32x2*        __restrict__ Gh,
    const f32x4*        __restrict__ M0,
    const f32x2*        __restrict__ M1,
    const unsigned int* __restrict__ WXY,
    const unsigned int* __restrict__ WZ,
    const int*          __restrict__ indices,
    float*              __restrict__ out)   // [N,6]: xx,yy,zz,xy,xz,yz
{
    int tid  = blockIdx.x * 256 + threadIdx.x;
    int node = tid >> 2;
    int q    = tid & 3;
    if (node >= N_NODES) return;

    u32x2 gip = Gh[node];
    f32x2 gi01 = unpack_h2(gip.x);
    f32x2 gi2_ = unpack_h2(gip.y);
    float gi0 = gi01.x, gi1 = gi01.y, gi2 = gi2_.x;

    int ebase = node * DEG + q * 4;
    i32x4 idx = __builtin_nontemporal_load((const i32x4*)(indices + ebase));
    u32x4 wxy = __builtin_nontemporal_load((const u32x4*)(WXY + ebase));
    u32x2 wzp = __builtin_nontemporal_load((const u32x2*)(WZ + (ebase >> 1)));

    // 4 independent gathers, all ~L2-hit (2.4 MB set)
    u32x2 gb[4];
    gb[0] = Gh[idx.x]; gb[1] = Gh[idx.y]; gb[2] = Gh[idx.z]; gb[3] = Gh[idx.w];

    float b00 = 0, b10 = 0, b20 = 0;
    float b01 = 0, b11 = 0, b21 = 0;
    float b02 = 0, b12 = 0, b22 = 0;
    unsigned int wxys[4] = {wxy.x, wxy.y, wxy.z, wxy.w};
    unsigned int wzs[2] = {wzp.x, wzp.y};
    #pragma unroll
    for (int k = 0; k < 4; ++k) {
        f32x2 wxyf = unpack_h2(wxys[k]);
        float wx = wxyf.x, wy = wxyf.y;
        f32x2 wzf = unpack_h2(wzs[k >> 1]);
        float wz = (k & 1) ? wzf.y : wzf.x;
        f32x2 gj01 = unpack_h2(gb[k].x);
        f32x2 gj2_ = unpack_h2(gb[k].y);
        float dv0 = gj01.x - gi0, dv1 = gj01.y - gi1, dv2 = gj2_.x - gi2;
        b00 += wx * dv0; b10 += wy * dv0; b20 += wz * dv0;
        b01 += wx * dv1; b11 += wy * dv1; b21 += wz * dv1;
        b02 += wx * dv2; b12 += wy * dv2; b22 += wz * dv2;
    }

    b00 = redux4(b00); b10 = redux4(b10); b20 = redux4(b20);
    b01 = redux4(b01); b11 = redux4(b11); b21 = redux4(b21);
    b02 = redux4(b02); b12 = redux4(b12); b22 = redux4(b22);

    if (q == 0) {
        f32x4 m0 = __builtin_nontemporal_load(M0 + node);
        f32x2 m1 = __builtin_nontemporal_load(M1 + node);
        float m00 = m0.x, m01 = m0.y, m02 = m0.z, m11 = m0.w;
        float m12 = m1.x, m22 = m1.y;
        float x00 = m00 * b00 + m01 * b10 + m02 * b20; // xx
        float x10 = m01 * b00 + m11 * b10 + m12 * b20; // xy
        float x20 = m02 * b00 + m12 * b10 + m22 * b20; // xz
        float x11 = m01 * b01 + m11 * b11 + m12 * b21; // yy
        float x21 = m02 * b01 + m12 * b11 + m22 * b21; // yz
        float x22 = m02 * b02 + m12 * b12 + m22 * b22; // zz
        f32x2* o2 = (f32x2*)(out + 6 * node);
        f32x2 o0 = {x00, x11};
        f32x2 o1 = {x22, x10};
        f32x2 o2v = {x20, x21};
        __builtin_nontemporal_store(o0,  o2 + 0);
        __builtin_nontemporal_store(o1,  o2 + 1);
        __builtin_nontemporal_store(o2v, o2 + 2);
    }
}

extern "C" void kernel_launch(void* const* d_in, const int* in_sizes, int n_in,
                              void* d_out, int out_size, void* d_ws, size_t ws_size,
                              hipStream_t stream) {
    const float* coords  = (const float*)d_in[0];
    const float* u       = (const float*)d_in[1];
    const int*   indices = (const int*)d_in[3];
    float*       out     = (float*)d_out;

    char* ws = (char*)d_ws;
    const size_t szP1  = (size_t)N_NODES * 16;           // 4.8 MB
    const size_t szGh  = (size_t)N_NODES * 8;            // 2.4 MB
    const size_t szM0  = (size_t)N_NODES * 16;           // 4.8 MB
    const size_t szM1  = (size_t)N_NODES * 8;            // 2.4 MB
    const size_t szWXY = (size_t)N_NODES * DEG * 4;      // 19.2 MB

    float4*       P1  = (float4*)ws;
    u32x2*        Gh  = (u32x2*)(ws + szP1);
    f32x4*        M0  = (f32x4*)(ws + szP1 + szGh);
    f32x2*        M1  = (f32x2*)(ws + szP1 + szGh + szM0);
    unsigned int* WXY = (unsigned int*)(ws + szP1 + szGh + szM0 + szM1);
    unsigned int* WZ  = (unsigned int*)(ws + szP1 + szGh + szM0 + szM1 + szWXY);

    const int block = 256;
    const int grid_nodes = (N_NODES + block - 1) / block;
    const int threads4 = N_NODES * 4;                    // 1.2M
    const int grid4 = (threads4 + block - 1) / block;    // 4688

    pack_p1<<<grid_nodes, block, 0, stream>>>(coords, u, P1);
    lsq_pass1<<<grid4, block, 0, stream>>>(P1, indices, Gh, M0, M1, WXY, WZ);
    lsq_pass2<<<grid4, block, 0, stream>>>(Gh, M0, M1, WXY, WZ, indices, out);
}